// Round 3
// baseline (1223.389 us; speedup 1.0000x reference)
//
#include <hip/hip_runtime.h>
#include <hip/hip_bf16.h>

#define HIDDEN 64
#define TN 64           // nodes per tile in fused kernel
#define APAD 132        // sA row stride in floats (132*4=528B: 16B-aligned, odd*16 -> A-reads 2-way/free)

// ---------------------------------------------------------------------------
// CSR build step 1: degree histogram over dst
// ---------------------------------------------------------------------------
__global__ __launch_bounds__(256) void k_hist(
    const int* __restrict__ ei, int* __restrict__ deg, int nEdges)
{
    for (int e = blockIdx.x * blockDim.x + threadIdx.x; e < nEdges;
         e += gridDim.x * blockDim.x) {
        atomicAdd(&deg[ei[nEdges + e]], 1);
    }
}

// ---------------------------------------------------------------------------
// CSR build step 2: exclusive scan deg -> rowPtr[0..n] and cursor[0..n-1]
// Single block, 1024 threads: per-thread serial segment + LDS Hillis-Steele.
// ---------------------------------------------------------------------------
__global__ __launch_bounds__(1024) void k_scan(
    const int* __restrict__ deg, int* __restrict__ rowPtr,
    int* __restrict__ cursor, int n)
{
    __shared__ int part[1024];
    const int t = threadIdx.x;
    const int seg = (n + 1023) / 1024;
    const int beg = t * seg;
    const int end = min(beg + seg, n);
    int s = 0;
    for (int i = beg; i < end; ++i) s += deg[i];
    part[t] = s;
    __syncthreads();
    for (int off = 1; off < 1024; off <<= 1) {
        int v = (t >= off) ? part[t - off] : 0;
        __syncthreads();
        part[t] += v;
        __syncthreads();
    }
    int run = (t == 0) ? 0 : part[t - 1];   // exclusive prefix
    for (int i = beg; i < end; ++i) {
        const int d = deg[i];
        rowPtr[i] = run;
        cursor[i] = run;
        run += d;
    }
    if (beg < n && end == n) rowPtr[n] = run;   // total edge count
}

// ---------------------------------------------------------------------------
// CSR build step 3: fill (order within a node's list is arbitrary)
// ---------------------------------------------------------------------------
__global__ __launch_bounds__(256) void k_fill(
    const int* __restrict__ ei, int* __restrict__ cursor,
    int* __restrict__ csrSrc, int nEdges)
{
    for (int e = blockIdx.x * blockDim.x + threadIdx.x; e < nEdges;
         e += gridDim.x * blockDim.x) {
        const int dst = ei[nEdges + e];
        const int pos = atomicAdd(&cursor[dst], 1);
        csrSrc[pos] = ei[e];
    }
}

// ---------------------------------------------------------------------------
// One GEMM K-pass: acc[r][j] += sA[tr*4+r][kOff+k] * sB[k][tc*4+j], k=0..63
// Fully unrolled; float4 LDS reads on both operands; all indices constant.
// ---------------------------------------------------------------------------
__device__ __forceinline__ void gemm_pass(
    const float (*sA)[APAD], const float (*sB)[HIDDEN],
    int tr, int tc, int kOff, float acc[4][4])
{
#pragma unroll
    for (int k4 = 0; k4 < 16; ++k4) {
        float A_[4][4], B_[4][4];
#pragma unroll
        for (int r = 0; r < 4; ++r) {
            const float4 t4 = *(const float4*)&sA[tr * 4 + r][kOff + k4 * 4];
            A_[r][0] = t4.x; A_[r][1] = t4.y; A_[r][2] = t4.z; A_[r][3] = t4.w;
        }
#pragma unroll
        for (int kk = 0; kk < 4; ++kk) {
            const float4 t4 = *(const float4*)&sB[k4 * 4 + kk][tc * 4];
            B_[kk][0] = t4.x; B_[kk][1] = t4.y; B_[kk][2] = t4.z; B_[kk][3] = t4.w;
        }
#pragma unroll
        for (int kk = 0; kk < 4; ++kk)
#pragma unroll
            for (int r = 0; r < 4; ++r)
#pragma unroll
                for (int j = 0; j < 4; ++j)
                    acc[r][j] = fmaf(A_[r][kk], B_[kk][j], acc[r][j]);
    }
}

// ---------------------------------------------------------------------------
// Fused SAGE layer. Per 64-node tile:
//   phase 1: CSR mean-gather -> sA[node][0..63], root row -> sA[node][64..127]
//   phase 2: out = sA[:,0:64]@Wl + bl + sA[:,64:128]@Wr  (two passes, sB reused)
// 256 threads = 4 waves (agg) = 16x16 thread grid (GEMM 4 nodes x 4 cols each).
// LDS = 64*132*4 + 64*64*4 = 50.2 KB -> 3 blocks/CU.
// ---------------------------------------------------------------------------
template <bool RELU>
__global__ __launch_bounds__(256) void k_fused(
    const float* __restrict__ xin,     // [N,64]
    const int* __restrict__ rowPtr,    // [N+1]
    const int* __restrict__ csrSrc,    // [E]
    const float* __restrict__ Wl,      // [64,64]
    const float* __restrict__ bl,      // [64]
    const float* __restrict__ Wr,      // [64,64]
    float* __restrict__ outp,          // [N,64]
    int nNodes)
{
    __shared__ __align__(16) float sA[TN][APAD];
    __shared__ __align__(16) float sB[HIDDEN][HIDDEN];

    const int w    = threadIdx.x >> 6;   // wave 0..3
    const int lane = threadIdx.x & 63;
    const int tr   = threadIdx.x >> 4;   // 0..15: node group
    const int tc   = threadIdx.x & 15;   // 0..15: col group

    // stage Wl (read in pass 1); no barrier needed until first read
    for (int i = threadIdx.x; i < HIDDEN * HIDDEN; i += 256)
        sB[i >> 6][i & 63] = Wl[i];

    float bias[4];
#pragma unroll
    for (int jj = 0; jj < 4; ++jj) bias[jj] = bl[tc * 4 + jj];

    const int base = blockIdx.x * TN;

    // ---- phase 1: aggregation (wave w owns nodes w*16 .. w*16+15) ----
    for (int n = w * 16; n < w * 16 + 16; ++n) {
        const int g = base + n;
        if (g < nNodes) {
            const int beg = rowPtr[g], end = rowPtr[g + 1];
            float acc0 = 0.f, acc1 = 0.f;
            int i = beg;
            for (; i + 7 < end; i += 8) {     // 8 gathers in flight, 2 chains
                const int s0 = csrSrc[i + 0], s1 = csrSrc[i + 1];
                const int s2 = csrSrc[i + 2], s3 = csrSrc[i + 3];
                const int s4 = csrSrc[i + 4], s5 = csrSrc[i + 5];
                const int s6 = csrSrc[i + 6], s7 = csrSrc[i + 7];
                acc0 += xin[s0 * HIDDEN + lane] + xin[s1 * HIDDEN + lane]
                      + xin[s2 * HIDDEN + lane] + xin[s3 * HIDDEN + lane];
                acc1 += xin[s4 * HIDDEN + lane] + xin[s5 * HIDDEN + lane]
                      + xin[s6 * HIDDEN + lane] + xin[s7 * HIDDEN + lane];
            }
            for (; i < end; ++i) acc0 += xin[csrSrc[i] * HIDDEN + lane];
            acc0 += acc1;
            const float inv = (end > beg) ? 1.0f / (float)(end - beg) : 1.0f;
            sA[n][lane]      = acc0 * inv;
            sA[n][64 + lane] = xin[g * HIDDEN + lane];
        } else {
            sA[n][lane]      = 0.f;
            sA[n][64 + lane] = 0.f;
        }
    }
    __syncthreads();            // sA complete AND sB(Wl) complete

    // ---- phase 2a: mean @ Wl ----
    float acc[4][4];
#pragma unroll
    for (int r = 0; r < 4; ++r)
#pragma unroll
        for (int jj = 0; jj < 4; ++jj) acc[r][jj] = bias[jj];
    gemm_pass(sA, sB, tr, tc, 0, acc);

    __syncthreads();            // all done reading sB(Wl)
    for (int i = threadIdx.x; i < HIDDEN * HIDDEN; i += 256)
        sB[i >> 6][i & 63] = Wr[i];
    __syncthreads();            // sB(Wr) ready

    // ---- phase 2b: root @ Wr ----
    gemm_pass(sA, sB, tr, tc, 64, acc);

    // ---- epilogue ----
#pragma unroll
    for (int r = 0; r < 4; ++r) {
        const int g = base + tr * 4 + r;
        if (g < nNodes) {
            float4 o;
            o.x = acc[r][0]; o.y = acc[r][1]; o.z = acc[r][2]; o.w = acc[r][3];
            if (RELU) {
                o.x = fmaxf(o.x, 0.f); o.y = fmaxf(o.y, 0.f);
                o.z = fmaxf(o.z, 0.f); o.w = fmaxf(o.w, 0.f);
            }
            *(float4*)&outp[g * HIDDEN + tc * 4] = o;
        }
    }
}

extern "C" void kernel_launch(void* const* d_in, const int* in_sizes, int n_in,
                              void* d_out, int out_size, void* d_ws, size_t ws_size,
                              hipStream_t stream)
{
    const float* x   = (const float*)d_in[0];
    const int*   ei  = (const int*)d_in[1];   // [2,E] int32 per harness convention
    const float* W1l = (const float*)d_in[2];
    const float* b1l = (const float*)d_in[3];
    const float* W1r = (const float*)d_in[4];
    const float* W2l = (const float*)d_in[5];
    const float* b2l = (const float*)d_in[6];
    const float* W2r = (const float*)d_in[7];
    float* out = (float*)d_out;

    const int nNodes = in_sizes[0] / HIDDEN;   // 100000
    const int nEdges = in_sizes[1] / 2;        // 1250000

    // workspace: h [N*64] f32 | deg [N+1] | rowPtr [N+1] | cursor [N] | csrSrc [E]
    float* h      = (float*)d_ws;
    int*   deg    = (int*)(h + (size_t)nNodes * HIDDEN);
    int*   rowPtr = deg + (nNodes + 1);
    int*   cursor = rowPtr + (nNodes + 1);
    int*   csrSrc = cursor + nNodes;

    const int nTiles = (nNodes + TN - 1) / TN;

    // ---- CSR build (shared by both layers) ----
    hipMemsetAsync(deg, 0, (size_t)(nNodes + 1) * sizeof(int), stream);
    k_hist<<<2048, 256, 0, stream>>>(ei, deg, nEdges);
    k_scan<<<1, 1024, 0, stream>>>(deg, rowPtr, cursor, nNodes);
    k_fill<<<2048, 256, 0, stream>>>(ei, cursor, csrSrc, nEdges);

    // ---- layer 1: h = relu(mean(x) @ W1l + b1l + x @ W1r) ----
    k_fused<true><<<nTiles, 256, 0, stream>>>(x, rowPtr, csrSrc, W1l, b1l, W1r,
                                              h, nNodes);
    // ---- layer 2: out = mean(h) @ W2l + b2l + h @ W2r ----
    k_fused<false><<<nTiles, 256, 0, stream>>>(h, rowPtr, csrSrc, W2l, b2l, W2r,
                                               out, nNodes);
}